// Round 4
// baseline (750.657 us; speedup 1.0000x reference)
//
#include <hip/hip_runtime.h>

#define DF   128    // feature dim
#define EPB  1024   // elements per scan block
#define MAXB 512    // max level-2 scan width (supports M <= 524288)

// ===========================================================================
// CSR build: count degrees -> exclusive scan -> place edge ids.
// Node space M = [66: 0..N6) [86: N6..2N6) [68: 2N6..2N6+N8) [88: ...+N8)
// Edge space  = [66: 0..E66) [86 ...) [68 ...) [88 ...)  (global gid)
// ===========================================================================

__global__ void __launch_bounds__(256) count_kernel(
    const int* __restrict__ ei66, const int* __restrict__ ei86,
    const int* __restrict__ ei68, const int* __restrict__ ei88,
    int E66, int E86, int E68, int E88, int N6, int N8,
    int* __restrict__ base)
{
    int Etot = E66 + E86 + E68 + E88;
    for (int gid = blockIdx.x * 256 + threadIdx.x; gid < Etot;
         gid += gridDim.x * 256) {
        int le = gid, nb, dst;
        if (le < E66)               { dst = ei66[2 * le + 1]; nb = 0; }
        else if ((le -= E66) < E86) { dst = ei86[2 * le + 1]; nb = N6; }
        else if ((le -= E86) < E68) { dst = ei68[2 * le + 1]; nb = 2 * N6; }
        else { le -= E68;             dst = ei88[2 * le + 1]; nb = 2 * N6 + N8; }
        atomicAdd(base + nb + dst, 1);
    }
}

__global__ void __launch_bounds__(256) scan1_kernel(
    int* __restrict__ data, int M, int* __restrict__ bsum)
{
    __shared__ int ts[256];
    int t = threadIdx.x;
    int i0 = blockIdx.x * EPB + t * 4;
    int v0 = 0, v1 = 0, v2 = 0, v3 = 0;
    if (i0 + 3 < M) {
        int4 q = *(const int4*)(data + i0);
        v0 = q.x; v1 = q.y; v2 = q.z; v3 = q.w;
    } else {
        if (i0     < M) v0 = data[i0];
        if (i0 + 1 < M) v1 = data[i0 + 1];
        if (i0 + 2 < M) v2 = data[i0 + 2];
    }
    int sum = v0 + v1 + v2 + v3;
    ts[t] = sum;
    __syncthreads();
    for (int off = 1; off < 256; off <<= 1) {
        int x = (t >= off) ? ts[t - off] : 0;
        __syncthreads();
        ts[t] += x;
        __syncthreads();
    }
    int excl = ts[t] - sum;
    if (t == 255) bsum[blockIdx.x] = ts[255];
    int w0 = excl, w1 = excl + v0, w2 = w1 + v1, w3 = w2 + v2;
    if (i0 + 3 < M) {
        *(int4*)(data + i0) = make_int4(w0, w1, w2, w3);
    } else {
        if (i0     < M) data[i0]     = w0;
        if (i0 + 1 < M) data[i0 + 1] = w1;
        if (i0 + 2 < M) data[i0 + 2] = w2;
    }
}

__global__ void __launch_bounds__(256) scan2_kernel(int* __restrict__ bsum, int nb)
{
    __shared__ int s[MAXB];
    int t = threadIdx.x;
    s[t]       = (t       < nb) ? bsum[t]       : 0;
    s[t + 256] = (t + 256 < nb) ? bsum[t + 256] : 0;
    __syncthreads();
    int o0 = s[t], o1 = s[t + 256];
    for (int off = 1; off < MAXB; off <<= 1) {
        int a = (t       >= off) ? s[t       - off] : 0;
        int b = (t + 256 >= off) ? s[t + 256 - off] : 0;
        __syncthreads();
        s[t] += a; s[t + 256] += b;
        __syncthreads();
    }
    if (t       < nb) bsum[t]       = s[t]       - o0;
    if (t + 256 < nb) bsum[t + 256] = s[t + 256] - o1;
}

__global__ void __launch_bounds__(256) scan3_kernel(
    int* __restrict__ data, int M, const int* __restrict__ bsum)
{
    int add = bsum[blockIdx.x];
    if (add == 0) return;
    int i0 = blockIdx.x * EPB + threadIdx.x * 4;
    if (i0 + 3 < M) {
        int4 q = *(const int4*)(data + i0);
        q.x += add; q.y += add; q.z += add; q.w += add;
        *(int4*)(data + i0) = q;
    } else {
        if (i0     < M) data[i0]     += add;
        if (i0 + 1 < M) data[i0 + 1] += add;
        if (i0 + 2 < M) data[i0 + 2] += add;
    }
}

__global__ void __launch_bounds__(256) fill_kernel(
    const int* __restrict__ ei66, const int* __restrict__ ei86,
    const int* __restrict__ ei68, const int* __restrict__ ei88,
    int E66, int E86, int E68, int E88, int N6, int N8,
    int* __restrict__ base, int* __restrict__ csr)
{
    int Etot = E66 + E86 + E68 + E88;
    for (int gid = blockIdx.x * 256 + threadIdx.x; gid < Etot;
         gid += gridDim.x * 256) {
        int le = gid, nb, dst;
        if (le < E66)               { dst = ei66[2 * le + 1]; nb = 0; }
        else if ((le -= E66) < E86) { dst = ei86[2 * le + 1]; nb = N6; }
        else if ((le -= E86) < E68) { dst = ei68[2 * le + 1]; nb = 2 * N6; }
        else { le -= E68;             dst = ei88[2 * le + 1]; nb = 2 * N6 + N8; }
        int pos = atomicAdd(base + nb + dst, 1);
        csr[pos] = gid;
    }
}

// ===========================================================================
// Fused gather-sum + GEMM + mean. 8 nodes/wave.
//  - Only `rows` in LDS (16 KB) -> occupancy 3 blocks/CU (launch_bounds).
//  - Software-pipelined gather: csr prefetch (depth 2) issued first, then
//    next-batch row loads, then current batch consumed -> the vmcnt wait at
//    the accumulate leaves ~16 loads in flight.
//  - GEMM streams W from global (L2-resident: 64 KB read by every block).
// After fill: start(g) = g ? base[g-1] : 0, end(g) = base[g].
// ===========================================================================
__global__ void __launch_bounds__(256, 3) gather_gemm_kernel(
    const float* __restrict__ msg, const float* __restrict__ Wm,
    const int* __restrict__ base, const int* __restrict__ csr,
    int gbase, int ebase, float* __restrict__ out, int N)
{
    __shared__ float rows[4][8][DF];     // 16 KB

    const int lane = threadIdx.x & 63;
    const int w    = threadIdx.x >> 6;
    const int gw   = (blockIdx.x << 2) + w;
    const int nws  = gridDim.x << 2;

    for (int n0 = gw * 8; n0 < N; n0 += nws * 8) {
        int st[8], en[8];
        #pragma unroll
        for (int r = 0; r < 8; ++r) {
            int n = n0 + r;
            if (n < N) {
                int g = gbase + n;
                st[r] = g ? base[g - 1] : 0;
                en[r] = base[g];
            } else { st[r] = 0; en[r] = 0; }
        }

        float2 a[8], v[8];
        int eid[8], eidn[8], ptr2[8];
        bool any = false;

        #pragma unroll
        for (int r = 0; r < 8; ++r) {
            a[r]   = make_float2(0.f, 0.f);
            eid[r] = (st[r] < en[r]) ? csr[st[r]] : -1;
            any |= (eid[r] >= 0);
        }
        #pragma unroll
        for (int r = 0; r < 8; ++r)
            eidn[r] = (st[r] + 1 < en[r]) ? csr[st[r] + 1] : -1;
        #pragma unroll
        for (int r = 0; r < 8; ++r) {
            ptr2[r] = st[r] + 2;
            if (eid[r] >= 0)
                v[r] = ((const float2*)(msg + (size_t)(eid[r] - ebase) * DF))[lane];
            else
                v[r] = make_float2(0.f, 0.f);
        }

        while (any) {
            // 1) csr prefetch, depth 2 (issued first -> shallow in vmcnt FIFO)
            int eidn2[8];
            #pragma unroll
            for (int r = 0; r < 8; ++r) {
                bool f = (eidn[r] >= 0) && (ptr2[r] < en[r]);
                eidn2[r] = f ? csr[ptr2[r]] : -1;
                ptr2[r] += f ? 1 : 0;
            }
            // 2) next-batch row loads
            float2 vn[8];
            #pragma unroll
            for (int r = 0; r < 8; ++r) {
                if (eidn[r] >= 0)
                    vn[r] = ((const float2*)(msg + (size_t)(eidn[r] - ebase) * DF))[lane];
                else
                    vn[r] = make_float2(0.f, 0.f);
            }
            // 3) consume current batch (waits only the oldest loads)
            any = false;
            #pragma unroll
            for (int r = 0; r < 8; ++r) {
                if (eid[r] >= 0) { a[r].x += v[r].x; a[r].y += v[r].y; }
                eid[r]  = eidn[r];
                v[r]    = vn[r];
                eidn[r] = eidn2[r];
                any |= (eid[r] >= 0);
            }
        }

        // transpose via wave-private LDS region (no barrier needed)
        #pragma unroll
        for (int r = 0; r < 8; ++r)
            ((float2*)rows[w][r])[lane] = a[r];

        // out[j] = sum_k row[k] * W[k][j]; lane owns cols 2*lane, 2*lane+1.
        // W streamed from global (L2-hot).
        float2 c[8];
        #pragma unroll
        for (int r = 0; r < 8; ++r) c[r] = make_float2(0.f, 0.f);

        #pragma unroll 4
        for (int k2 = 0; k2 < DF / 2; ++k2) {
            float2 w0 = *(const float2*)(Wm + (size_t)(2 * k2)     * DF + 2 * lane);
            float2 w1 = *(const float2*)(Wm + (size_t)(2 * k2 + 1) * DF + 2 * lane);
            #pragma unroll
            for (int r = 0; r < 8; ++r) {
                float2 rv = ((const float2*)rows[w][r])[k2];   // LDS broadcast
                c[r].x += rv.x * w0.x + rv.y * w1.x;
                c[r].y += rv.x * w0.y + rv.y * w1.y;
            }
        }

        #pragma unroll
        for (int r = 0; r < 8; ++r) {
            if (n0 + r < N) {
                int   d   = en[r] - st[r];
                float inv = (d > 0) ? (1.0f / (float)d) : 0.0f;
                ((float2*)(out + (size_t)(n0 + r) * 256))[lane] =
                    make_float2(c[r].x * inv, c[r].y * inv);
            }
        }
    }
}

// masks from post-fill base diffs: num_types = (deg_a>0) + (deg_b>0)
__global__ void __launch_bounds__(256) mask_kernel(
    const int* __restrict__ base, float* __restrict__ nt6,
    float* __restrict__ nt8, int N6, int N8)
{
    int i = blockIdx.x * blockDim.x + threadIdx.x;
    if (i < N6) {
        int g66 = i, g86 = N6 + i;
        int d66 = base[g66] - (g66 ? base[g66 - 1] : 0);
        int d86 = base[g86] - base[g86 - 1];
        nt6[i] = (float)((d66 > 0) + (d86 > 0));
    }
    if (i < N8) {
        int g68 = 2 * N6 + i, g88 = 2 * N6 + N8 + i;
        int d68 = base[g68] - base[g68 - 1];
        int d88 = base[g88] - base[g88 - 1];
        nt8[i] = (float)((d68 > 0) + (d88 > 0));
    }
}

extern "C" void kernel_launch(void* const* d_in, const int* in_sizes, int n_in,
                              void* d_out, int out_size, void* d_ws, size_t ws_size,
                              hipStream_t stream)
{
    const float* msg66 = (const float*)d_in[0];
    const float* msg68 = (const float*)d_in[1];
    const float* msg86 = (const float*)d_in[2];
    const float* msg88 = (const float*)d_in[3];
    const float* W66   = (const float*)d_in[4];
    const float* W68   = (const float*)d_in[5];
    const float* W86   = (const float*)d_in[6];
    const float* W88   = (const float*)d_in[7];
    const int*   ei66  = (const int*)d_in[8];
    const int*   ei68  = (const int*)d_in[9];
    const int*   ei86  = (const int*)d_in[10];
    const int*   ei88  = (const int*)d_in[11];

    int E66 = in_sizes[8]  / 2;
    int E68 = in_sizes[9]  / 2;
    int E86 = in_sizes[10] / 2;
    int E88 = in_sizes[11] / 2;
    int Etot = E66 + E86 + E68 + E88;

    size_t S  = (size_t)out_size / 257;       // out = 257*(N6+N8)
    int    N6 = (int)(S / 2);
    int    N8 = (int)(S - S / 2);
    int    M  = 2 * N6 + 2 * N8;

    float* out  = (float*)d_out;
    float* out6 = out;                          // (N6, 2, 128)
    float* out8 = out + (size_t)N6 * 256;       // (N8, 2, 128)
    float* nt6  = out + (size_t)(N6 + N8) * 256;
    float* nt8  = nt6 + N6;

    int* base = (int*)d_ws;                     // [M]
    int* bsum = base + M;                       // [MAXB]
    int* csr  = bsum + MAXB;                    // [Etot]

    int NB = (M + EPB - 1) / EPB;               // scan chunks (M=400K -> 391)

    hipMemsetAsync(base, 0, (size_t)M * sizeof(int), stream);

    int eg = (Etot + 255) / 256;
    if (eg > 4096) eg = 4096;
    count_kernel<<<dim3(eg), dim3(256), 0, stream>>>(
        ei66, ei86, ei68, ei88, E66, E86, E68, E88, N6, N8, base);

    scan1_kernel<<<dim3(NB), dim3(256), 0, stream>>>(base, M, bsum);
    scan2_kernel<<<dim3(1),  dim3(256), 0, stream>>>(bsum, NB);
    scan3_kernel<<<dim3(NB), dim3(256), 0, stream>>>(base, M, bsum);

    fill_kernel<<<dim3(eg), dim3(256), 0, stream>>>(
        ei66, ei86, ei68, ei88, E66, E86, E68, E88, N6, N8, base, csr);

    int eb66 = 0, eb86 = E66, eb68 = E66 + E86, eb88 = E66 + E86 + E68;
    dim3 b(256), g(1024);
    gather_gemm_kernel<<<g, b, 0, stream>>>(msg66, W66, base, csr, 0,           eb66, out6,       N6);
    gather_gemm_kernel<<<g, b, 0, stream>>>(msg86, W86, base, csr, N6,          eb86, out6 + 128, N6);
    gather_gemm_kernel<<<g, b, 0, stream>>>(msg68, W68, base, csr, 2 * N6,      eb68, out8,       N8);
    gather_gemm_kernel<<<g, b, 0, stream>>>(msg88, W88, base, csr, 2 * N6 + N8, eb88, out8 + 128, N8);

    int Nmax = (N6 > N8) ? N6 : N8;
    mask_kernel<<<dim3((Nmax + 255) / 256), dim3(256), 0, stream>>>(
        base, nt6, nt8, N6, N8);
}